// Round 4
// baseline (25852.948 us; speedup 1.0000x reference)
//
#include <hip/hip_runtime.h>
#include <hip/hip_bf16.h>

#define RNN_B 64
#define RNN_S 512
#define RNN_H 1024
#define NBLK 64
#define FLAG_STRIDE 32   // one flag per 128B line
#define OUTS_ELEMS ((size_t)RNN_B * RNN_S * RNN_H)

typedef __attribute__((ext_vector_type(4))) float f32x4;
typedef __attribute__((ext_vector_type(8))) short bf16x8;

__device__ __forceinline__ short f2bf(float f) {
  union { float f; unsigned u; } v; v.f = f;
  return (short)((v.u + 0x7FFFu + ((v.u >> 16) & 1u)) >> 16);
}
__device__ __forceinline__ float bf2f(short h) {
  union { unsigned u; float f; } v; v.u = ((unsigned)(unsigned short)h) << 16;
  return v.f;
}

__device__ __forceinline__ f32x4 mfma16(bf16x8 a, bf16x8 b, f32x4 c) {
  return __builtin_amdgcn_mfma_f32_16x16x32_bf16(a, b, c, 0, 0, 0);
}

// ---- coherent-by-construction cross-block ops (no wbl2/inv fences anywhere) ----
// 2B write-through store to the coherence point (LLC): leaves nothing dirty in L2.
__device__ __forceinline__ void st_sys_u16(void* p, unsigned v) {
  asm volatile("global_store_short %0, %1, off sc0 sc1" :: "v"(p), "v"(v) : "memory");
}
// 16B fragment load via two 8B system-scope relaxed atomics (sc0 sc1, L1/L2-bypass,
// compiler-tracked vmcnt so normal scheduling/latency-hiding applies).
__device__ __forceinline__ bf16x8 ld_frag_sys(const short* p) {
  union { bf16x8 v; unsigned long long u[2]; } r;
  r.u[0] = __hip_atomic_load((const unsigned long long*)p,     __ATOMIC_RELAXED, __HIP_MEMORY_SCOPE_SYSTEM);
  r.u[1] = __hip_atomic_load((const unsigned long long*)(p+4), __ATOMIC_RELAXED, __HIP_MEMORY_SCOPE_SYSTEM);
  return r.v;
}

// split 8 fp32 -> hi bf16x8 + lo bf16x8 (two-term bf16 expansion, ~16 mantissa bits)
__device__ __forceinline__ void cvt8_hl(const float* f, bf16x8* hi, bf16x8* lo) {
  #pragma unroll
  for (int i = 0; i < 8; ++i) {
    short h = f2bf(f[i]);
    (*hi)[i] = h;
    (*lo)[i] = f2bf(f[i] - bf2f(h));
  }
}

// ---------- Kernel 1: A0 = x @ W_ih0^T + b_ih0 + b_hh0 (split-bf16 3-pass, ~fp32 accurate)
__global__ __launch_bounds__(256) void a0_gemm(
    const float* __restrict__ x, const float* __restrict__ Wih0,
    const float* __restrict__ bih0, const float* __restrict__ bhh0,
    float* __restrict__ A0, unsigned* __restrict__ flags)
{
  if (blockIdx.x == 0) {
    for (int i = threadIdx.x; i < NBLK * FLAG_STRIDE; i += 256)
      __hip_atomic_store(&flags[i], 0u, __ATOMIC_RELAXED, __HIP_MEMORY_SCOPE_SYSTEM);
  }
  const int bn = blockIdx.x & 7;     // 8 N-tiles of 128
  const int bm = blockIdx.x >> 3;    // 256 M-tiles of 128
  const int tid = threadIdx.x;
  const int lane = tid & 63;
  const int w = tid >> 6;
  const int wr = w >> 1, wc = w & 1;
  const int l15 = lane & 15, lq = lane >> 4;

  __shared__ short As[2][128][40];   // [hi/lo][row][k], +8 pad
  __shared__ short Bs[2][128][40];

  f32x4 acc[4][4] = {};

  const int sr = tid >> 1;
  const int sc = (tid & 1) << 4;
  const float* xp = x + (size_t)(bm * 128 + sr) * RNN_H + sc;
  const float* wp = Wih0 + (size_t)(bn * 128 + sr) * RNN_H + sc;

  for (int k0 = 0; k0 < RNN_H; k0 += 32) {
    float xa[16], wa[16];
    #pragma unroll
    for (int j = 0; j < 4; ++j) {
      *(float4*)&xa[j * 4] = *(const float4*)(xp + k0 + j * 4);
      *(float4*)&wa[j * 4] = *(const float4*)(wp + k0 + j * 4);
    }
    __syncthreads();   // previous iter's LDS reads done
    bf16x8 h0, l0, h1, l1;
    cvt8_hl(&xa[0], &h0, &l0); cvt8_hl(&xa[8], &h1, &l1);
    *(bf16x8*)&As[0][sr][sc] = h0; *(bf16x8*)&As[1][sr][sc] = l0;
    *(bf16x8*)&As[0][sr][sc + 8] = h1; *(bf16x8*)&As[1][sr][sc + 8] = l1;
    cvt8_hl(&wa[0], &h0, &l0); cvt8_hl(&wa[8], &h1, &l1);
    *(bf16x8*)&Bs[0][sr][sc] = h0; *(bf16x8*)&Bs[1][sr][sc] = l0;
    *(bf16x8*)&Bs[0][sr][sc + 8] = h1; *(bf16x8*)&Bs[1][sr][sc + 8] = l1;
    __syncthreads();
    bf16x8 ah[4], al[4], bh[4], bl[4];
    #pragma unroll
    for (int i = 0; i < 4; ++i) {
      ah[i] = *(const bf16x8*)&As[0][wr * 64 + i * 16 + l15][lq * 8];
      al[i] = *(const bf16x8*)&As[1][wr * 64 + i * 16 + l15][lq * 8];
    }
    #pragma unroll
    for (int j = 0; j < 4; ++j) {
      bh[j] = *(const bf16x8*)&Bs[0][wc * 64 + j * 16 + l15][lq * 8];
      bl[j] = *(const bf16x8*)&Bs[1][wc * 64 + j * 16 + l15][lq * 8];
    }
    #pragma unroll
    for (int i = 0; i < 4; ++i)
      #pragma unroll
      for (int j = 0; j < 4; ++j) {
        acc[i][j] = mfma16(ah[i], bh[j], acc[i][j]);
        acc[i][j] = mfma16(al[i], bh[j], acc[i][j]);
        acc[i][j] = mfma16(ah[i], bl[j], acc[i][j]);
      }
  }

  #pragma unroll
  for (int j = 0; j < 4; ++j) {
    const int col = bn * 128 + wc * 64 + j * 16 + l15;
    const float bias = bih0[col] + bhh0[col];
    #pragma unroll
    for (int i = 0; i < 4; ++i) {
      const int row0 = bm * 128 + wr * 64 + i * 16 + lq * 4;
      #pragma unroll
      for (int r = 0; r < 4; ++r)
        A0[(size_t)(row0 + r) * RNN_H + col] = acc[i][j][r] + bias;
    }
  }
}

// ---------- grid barrier: NO cache-maintenance fences. All cross-block data moves
// via sc0/sc1 (coherence-point) ops, so the barrier is just: drain stores ->
// block-arrival flag store -> 64-lane poll of all flags.
__device__ __forceinline__ void gbar(unsigned* flags, unsigned target, int bid) {
  asm volatile("s_waitcnt vmcnt(0)" ::: "memory");  // drain this wave's asm h-stores
  __syncthreads();                                   // all waves of block arrived+drained
  if (threadIdx.x == 0)
    __hip_atomic_store(&flags[bid * FLAG_STRIDE], target,
                       __ATOMIC_RELAXED, __HIP_MEMORY_SCOPE_SYSTEM);
  if (threadIdx.x < 64) {
    const unsigned* f = &flags[threadIdx.x * FLAG_STRIDE];
    while (!__all(__hip_atomic_load(f, __ATOMIC_RELAXED,
                                    __HIP_MEMORY_SCOPE_SYSTEM) >= target))
      __builtin_amdgcn_s_sleep(1);
  }
  __syncthreads();
}

// ---------- Kernel 2: persistent pipelined recurrence (h carried as bf16 hi+lo pairs)
__global__ __launch_bounds__(512) void rnn_rec(
    const float* __restrict__ Whh0,
    const float* __restrict__ Wih1, const float* __restrict__ bih1,
    const float* __restrict__ Whh1, const float* __restrict__ bhh1,
    float* outs,             // d_out: A0 (read), layer-1 outs (write), hT tail
    short* __restrict__ h0hi, short* __restrict__ h0lo,
    short* __restrict__ h1hi, short* __restrict__ h1lo,
    unsigned* flags)
{
  const int bid = blockIdx.x;
  const int n0 = bid * 16;
  const int tid = threadIdx.x;
  const int w = tid >> 6;
  const int lane = tid & 63;
  const int l15 = lane & 15;
  const int lq = lane >> 4;
  const int mt = (w & 3) * 16;      // batch-row tile for this wave
  const bool isL1 = w >= 4;
  const int BH = RNN_B * RNN_H;

  __shared__ short Ws[3 * 16 * 1024];   // 96 KiB: [Whh0 | Wih1 | Whh1], swizzled

  {
    const float* srcs[3] = { Whh0, Wih1, Whh1 };
    const int n = tid >> 5;             // 0..15
    const int kb = (tid & 31) * 32;     // 0..992
    #pragma unroll
    for (int mi = 0; mi < 3; ++mi) {
      const float* src = srcs[mi] + (size_t)(n0 + n) * RNN_H + kb;
      short* dst = &Ws[mi * 16 * 1024 + n * 1024];
      #pragma unroll
      for (int j = 0; j < 4; ++j) {
        float4 f0 = *(const float4*)(src + j * 8);
        float4 f1 = *(const float4*)(src + j * 8 + 4);
        float tmp[8]; *(float4*)&tmp[0] = f0; *(float4*)&tmp[4] = f1;
        bf16x8 hv, lv; cvt8_hl(tmp, &hv, &lv);
        const int c = (kb >> 3) + j;
        *(bf16x8*)&dst[((c ^ (n & 7)) << 3)] = hv;
      }
    }
  }
  const float bias1v = bih1[n0 + l15] + bhh1[n0 + l15];
  float* hT = outs + OUTS_ELEMS;
  __syncthreads();

  float a0v[4];
  if (!isL1) {
    #pragma unroll
    for (int r = 0; r < 4; ++r)
      a0v[r] = outs[((size_t)(mt + lq * 4 + r) * RNN_S + 0) * RNN_H + n0 + l15];
  }

  for (int p = 0; p <= RNN_S; ++p) {
    if (!isL1) {
      if (p < RNN_S) {
        // layer 0: h0(p) = tanh(A0[:,p,:] + h0(p-1) @ Whh0^T) for cols n0..n0+15
        f32x4 acc0 = { a0v[0], a0v[1], a0v[2], a0v[3] };
        f32x4 acc1 = {}, acc2 = {}, acc3 = {};
        if (p > 0) {
          const size_t hb = (size_t)((p - 1) & 1) * BH + (mt + l15) * RNN_H + lq * 8;
          const short* hh = h0hi + hb;
          const short* hl = h0lo + hb;
          const short* wrow = &Ws[l15 * 1024];
          const int swz = l15 & 7;
          #pragma unroll
          for (int ks = 0; ks < 16; ++ks) {   // 4 independent chains for ILP
            const int c0 = ((ks * 4 + lq) ^ swz) << 3;
            const int c1 = (((ks + 16) * 4 + lq) ^ swz) << 3;
            acc0 = mfma16(ld_frag_sys(hh + ks * 32),        *(const bf16x8*)(wrow + c0), acc0);
            acc1 = mfma16(ld_frag_sys(hh + (ks + 16) * 32), *(const bf16x8*)(wrow + c1), acc1);
            acc2 = mfma16(ld_frag_sys(hl + ks * 32),        *(const bf16x8*)(wrow + c0), acc2);
            acc3 = mfma16(ld_frag_sys(hl + (ks + 16) * 32), *(const bf16x8*)(wrow + c1), acc3);
          }
        }
        acc0 += acc1; acc2 += acc3; acc0 += acc2;
        float vals[4];
        #pragma unroll
        for (int r = 0; r < 4; ++r) vals[r] = tanhf(acc0[r]);
        const size_t hd = (size_t)(p & 1) * BH;
        #pragma unroll
        for (int r = 0; r < 4; ++r) {
          const int idx = (mt + lq * 4 + r) * RNN_H + n0 + l15;
          short hi = f2bf(vals[r]);
          st_sys_u16(&h0hi[hd + idx], (unsigned)(unsigned short)hi);
          st_sys_u16(&h0lo[hd + idx], (unsigned)(unsigned short)f2bf(vals[r] - bf2f(hi)));
        }
        if (p == RNN_S - 1) {
          #pragma unroll
          for (int r = 0; r < 4; ++r)
            hT[(size_t)(mt + lq * 4 + r) * RNN_H + n0 + l15] = vals[r];
        }
        if (p + 1 < RNN_S) {   // prefetch next A0 (barrier-independent; drains inside gbar)
          #pragma unroll
          for (int r = 0; r < 4; ++r)
            a0v[r] = outs[((size_t)(mt + lq * 4 + r) * RNN_S + (p + 1)) * RNN_H + n0 + l15];
        }
      }
    } else {
      if (p >= 1) {
        // layer 1: t = p-1: h1(t) = tanh(b1 + h0(t) @ Wih1^T + h1(t-1) @ Whh1^T)
        const int t = p - 1;
        f32x4 acc0 = { bias1v, bias1v, bias1v, bias1v };
        f32x4 acc1 = {}, acc2 = {}, acc3 = {};
        const size_t h0o = (size_t)(t & 1) * BH + (mt + l15) * RNN_H + lq * 8;
        const short* h0h = h0hi + h0o;
        const short* h0l = h0lo + h0o;
        const short* wih = &Ws[16 * 1024 + l15 * 1024];
        const short* whh = &Ws[2 * 16 * 1024 + l15 * 1024];
        const int swz = l15 & 7;
        if (t > 0) {
          const size_t h1o = (size_t)((t - 1) & 1) * BH + (mt + l15) * RNN_H + lq * 8;
          const short* h1h = h1hi + h1o;
          const short* h1l = h1lo + h1o;
          #pragma unroll
          for (int ks = 0; ks < 32; ++ks) {   // 4 independent chains
            const int c = ((ks * 4 + lq) ^ swz) << 3;
            acc0 = mfma16(ld_frag_sys(h0h + ks * 32), *(const bf16x8*)(wih + c), acc0);
            acc1 = mfma16(ld_frag_sys(h0l + ks * 32), *(const bf16x8*)(wih + c), acc1);
            acc2 = mfma16(ld_frag_sys(h1h + ks * 32), *(const bf16x8*)(whh + c), acc2);
            acc3 = mfma16(ld_frag_sys(h1l + ks * 32), *(const bf16x8*)(whh + c), acc3);
          }
        } else {
          #pragma unroll
          for (int ks = 0; ks < 32; ++ks) {
            const int c = ((ks * 4 + lq) ^ swz) << 3;
            acc0 = mfma16(ld_frag_sys(h0h + ks * 32), *(const bf16x8*)(wih + c), acc0);
            acc1 = mfma16(ld_frag_sys(h0l + ks * 32), *(const bf16x8*)(wih + c), acc1);
          }
        }
        acc0 += acc1; acc2 += acc3; acc0 += acc2;
        float vals[4];
        #pragma unroll
        for (int r = 0; r < 4; ++r) vals[r] = tanhf(acc0[r]);
        const size_t hd = (size_t)(t & 1) * BH;
        #pragma unroll
        for (int r = 0; r < 4; ++r) {
          const int b = mt + lq * 4 + r;
          const int idx = b * RNN_H + n0 + l15;
          short hi = f2bf(vals[r]);
          st_sys_u16(&h1hi[hd + idx], (unsigned)(unsigned short)hi);
          st_sys_u16(&h1lo[hd + idx], (unsigned)(unsigned short)f2bf(vals[r] - bf2f(hi)));
          outs[((size_t)b * RNN_S + t) * RNN_H + n0 + l15] = vals[r];
        }
        if (t == RNN_S - 1) {
          #pragma unroll
          for (int r = 0; r < 4; ++r)
            hT[(size_t)RNN_B * RNN_H + (mt + lq * 4 + r) * RNN_H + n0 + l15] = vals[r];
        }
      }
    }
    if (p < RNN_S) gbar(flags, (unsigned)(p + 1), bid);
  }
}

extern "C" void kernel_launch(void* const* d_in, const int* in_sizes, int n_in,
                              void* d_out, int out_size, void* d_ws, size_t ws_size,
                              hipStream_t stream) {
  const float* x    = (const float*)d_in[0];
  const float* Wih0 = (const float*)d_in[1];
  const float* bih0 = (const float*)d_in[2];
  const float* Whh0 = (const float*)d_in[3];
  const float* bhh0 = (const float*)d_in[4];
  const float* Wih1 = (const float*)d_in[5];
  const float* bih1 = (const float*)d_in[6];
  const float* Whh1 = (const float*)d_in[7];
  const float* bhh1 = (const float*)d_in[8];
  float* outs = (float*)d_out;

  const int BH2 = 2 * RNN_B * RNN_H;               // elems per ping-pong buffer
  short* h0hi = (short*)d_ws;
  short* h0lo = h0hi + BH2;
  short* h1hi = h0lo + BH2;
  short* h1lo = h1hi + BH2;
  unsigned* flags = (unsigned*)((char*)d_ws + ((size_t)4 * BH2 * sizeof(short)));

  a0_gemm<<<2048, 256, 0, stream>>>(x, Wih0, bih0, bhh0, outs, flags);
  rnn_rec<<<NBLK, 512, 0, stream>>>(Whh0, Wih1, bih1, Whh1, bhh1, outs,
                                    h0hi, h0lo, h1hi, h1lo, flags);
}

// Round 5
// 13022.871 us; speedup vs baseline: 1.9852x; 1.9852x over previous
//
#include <hip/hip_runtime.h>
#include <hip/hip_bf16.h>

#define RNN_B 64
#define RNN_S 512
#define RNN_H 1024
#define NBLK 64
#define FLAG_STRIDE 32   // one flag per 128B line
#define OUTS_ELEMS ((size_t)RNN_B * RNN_S * RNN_H)

typedef __attribute__((ext_vector_type(4))) float f32x4;
typedef __attribute__((ext_vector_type(8))) short bf16x8;
typedef __attribute__((ext_vector_type(4))) int i32x4;

// CK-style raw buffer load intrinsic (coalesced dwordx4, cachepolicy arg).
// cachepolicy 17 = SC0|SC1 on gfx940/gfx950: bypass L1+L2, read the
// coherence point (LLC) -> always-fresh cross-XCD data, full burst BW,
// compiler-tracked vmcnt (deep pipelining preserved).
__device__ f32x4 __rnn_rawbufload_x4(i32x4 srsrc, int voffset, int soffset,
                                     int cachepolicy) __asm("llvm.amdgcn.raw.buffer.load.v4f32");

__device__ __forceinline__ i32x4 make_srd(const void* p, unsigned bytes) {
  i32x4 r;
  r[0] = (int)(unsigned)(unsigned long long)p;
  r[1] = (int)((unsigned long long)p >> 32);   // stride=0
  r[2] = (int)bytes;                            // num_records (bytes)
  r[3] = 0x00020000;                            // raw untyped dword
  return r;
}

__device__ __forceinline__ bf16x8 ld_h(i32x4 srd, int byteoff) {
  union { f32x4 f; bf16x8 s; } u;
  u.f = __rnn_rawbufload_x4(srd, byteoff, 0, 17 /*sc0|sc1*/);
  return u.s;
}

__device__ __forceinline__ short f2bf(float f) {
  union { float f; unsigned u; } v; v.f = f;
  return (short)((v.u + 0x7FFFu + ((v.u >> 16) & 1u)) >> 16);
}
__device__ __forceinline__ float bf2f(short h) {
  union { unsigned u; float f; } v; v.u = ((unsigned)(unsigned short)h) << 16;
  return v.f;
}

__device__ __forceinline__ f32x4 mfma16(bf16x8 a, bf16x8 b, f32x4 c) {
  return __builtin_amdgcn_mfma_f32_16x16x32_bf16(a, b, c, 0, 0, 0);
}

// 2B write-through store to the coherence point: leaves nothing dirty in L2,
// so no wbl2/inv fences are ever needed for the h hand-off.
__device__ __forceinline__ void st_sys_u16(void* p, unsigned v) {
  asm volatile("global_store_short %0, %1, off sc0 sc1" :: "v"(p), "v"(v) : "memory");
}

// split 8 fp32 -> hi bf16x8 + lo bf16x8 (two-term bf16 expansion, ~16 mantissa bits)
__device__ __forceinline__ void cvt8_hl(const float* f, bf16x8* hi, bf16x8* lo) {
  #pragma unroll
  for (int i = 0; i < 8; ++i) {
    short h = f2bf(f[i]);
    (*hi)[i] = h;
    (*lo)[i] = f2bf(f[i] - bf2f(h));
  }
}

// ---------- Kernel 1: A0 = x @ W_ih0^T + b_ih0 + b_hh0 (split-bf16 3-pass, ~fp32 accurate)
__global__ __launch_bounds__(256) void a0_gemm(
    const float* __restrict__ x, const float* __restrict__ Wih0,
    const float* __restrict__ bih0, const float* __restrict__ bhh0,
    float* __restrict__ A0, unsigned* __restrict__ flags)
{
  if (blockIdx.x == 0) {
    for (int i = threadIdx.x; i < NBLK * FLAG_STRIDE; i += 256)
      __hip_atomic_store(&flags[i], 0u, __ATOMIC_RELAXED, __HIP_MEMORY_SCOPE_SYSTEM);
  }
  const int bn = blockIdx.x & 7;     // 8 N-tiles of 128
  const int bm = blockIdx.x >> 3;    // 256 M-tiles of 128
  const int tid = threadIdx.x;
  const int lane = tid & 63;
  const int w = tid >> 6;
  const int wr = w >> 1, wc = w & 1;
  const int l15 = lane & 15, lq = lane >> 4;

  __shared__ short As[2][128][40];   // [hi/lo][row][k], +8 pad
  __shared__ short Bs[2][128][40];

  f32x4 acc[4][4] = {};

  const int sr = tid >> 1;
  const int sc = (tid & 1) << 4;
  const float* xp = x + (size_t)(bm * 128 + sr) * RNN_H + sc;
  const float* wp = Wih0 + (size_t)(bn * 128 + sr) * RNN_H + sc;

  for (int k0 = 0; k0 < RNN_H; k0 += 32) {
    float xa[16], wa[16];
    #pragma unroll
    for (int j = 0; j < 4; ++j) {
      *(float4*)&xa[j * 4] = *(const float4*)(xp + k0 + j * 4);
      *(float4*)&wa[j * 4] = *(const float4*)(wp + k0 + j * 4);
    }
    __syncthreads();   // previous iter's LDS reads done
    bf16x8 h0, l0, h1, l1;
    cvt8_hl(&xa[0], &h0, &l0); cvt8_hl(&xa[8], &h1, &l1);
    *(bf16x8*)&As[0][sr][sc] = h0; *(bf16x8*)&As[1][sr][sc] = l0;
    *(bf16x8*)&As[0][sr][sc + 8] = h1; *(bf16x8*)&As[1][sr][sc + 8] = l1;
    cvt8_hl(&wa[0], &h0, &l0); cvt8_hl(&wa[8], &h1, &l1);
    *(bf16x8*)&Bs[0][sr][sc] = h0; *(bf16x8*)&Bs[1][sr][sc] = l0;
    *(bf16x8*)&Bs[0][sr][sc + 8] = h1; *(bf16x8*)&Bs[1][sr][sc + 8] = l1;
    __syncthreads();
    bf16x8 ah[4], al[4], bh[4], bl[4];
    #pragma unroll
    for (int i = 0; i < 4; ++i) {
      ah[i] = *(const bf16x8*)&As[0][wr * 64 + i * 16 + l15][lq * 8];
      al[i] = *(const bf16x8*)&As[1][wr * 64 + i * 16 + l15][lq * 8];
    }
    #pragma unroll
    for (int j = 0; j < 4; ++j) {
      bh[j] = *(const bf16x8*)&Bs[0][wc * 64 + j * 16 + l15][lq * 8];
      bl[j] = *(const bf16x8*)&Bs[1][wc * 64 + j * 16 + l15][lq * 8];
    }
    #pragma unroll
    for (int i = 0; i < 4; ++i)
      #pragma unroll
      for (int j = 0; j < 4; ++j) {
        acc[i][j] = mfma16(ah[i], bh[j], acc[i][j]);
        acc[i][j] = mfma16(al[i], bh[j], acc[i][j]);
        acc[i][j] = mfma16(ah[i], bl[j], acc[i][j]);
      }
  }

  #pragma unroll
  for (int j = 0; j < 4; ++j) {
    const int col = bn * 128 + wc * 64 + j * 16 + l15;
    const float bias = bih0[col] + bhh0[col];
    #pragma unroll
    for (int i = 0; i < 4; ++i) {
      const int row0 = bm * 128 + wr * 64 + i * 16 + lq * 4;
      #pragma unroll
      for (int r = 0; r < 4; ++r)
        A0[(size_t)(row0 + r) * RNN_H + col] = acc[i][j][r] + bias;
    }
  }
}

// ---------- grid barrier: no cache-maintenance fences. All cross-block data moves
// via sc0/sc1 coherence-point ops; barrier = drain stores -> flag store -> poll.
__device__ __forceinline__ void gbar(unsigned* flags, unsigned target, int bid) {
  asm volatile("s_waitcnt vmcnt(0)" ::: "memory");  // drain this wave's asm h-stores
  __syncthreads();                                   // all waves arrived + drained
  if (threadIdx.x == 0)
    __hip_atomic_store(&flags[bid * FLAG_STRIDE], target,
                       __ATOMIC_RELAXED, __HIP_MEMORY_SCOPE_SYSTEM);
  if (threadIdx.x < 64) {
    const unsigned* f = &flags[threadIdx.x * FLAG_STRIDE];
    while (!__all(__hip_atomic_load(f, __ATOMIC_RELAXED,
                                    __HIP_MEMORY_SCOPE_SYSTEM) >= target))
      __builtin_amdgcn_s_sleep(1);
  }
  __syncthreads();
}

// ---------- Kernel 2: persistent pipelined recurrence (h carried as bf16 hi+lo pairs)
__global__ __launch_bounds__(512) void rnn_rec(
    const float* __restrict__ Whh0,
    const float* __restrict__ Wih1, const float* __restrict__ bih1,
    const float* __restrict__ Whh1, const float* __restrict__ bhh1,
    float* outs,             // d_out: A0 (read), layer-1 outs (write), hT tail
    short* __restrict__ h0hi, short* __restrict__ h0lo,
    short* __restrict__ h1hi, short* __restrict__ h1lo,
    unsigned* flags)
{
  const int bid = blockIdx.x;
  const int n0 = bid * 16;
  const int tid = threadIdx.x;
  const int w = tid >> 6;
  const int lane = tid & 63;
  const int l15 = lane & 15;
  const int lq = lane >> 4;
  const int mt = (w & 3) * 16;      // batch-row tile for this wave
  const bool isL1 = w >= 4;
  const int BH = RNN_B * RNN_H;
  const unsigned HBYTES = 2u * (unsigned)BH * 2u;   // bytes per ping-pong h buffer

  const i32x4 srd_h0hi = make_srd(h0hi, HBYTES);
  const i32x4 srd_h0lo = make_srd(h0lo, HBYTES);
  const i32x4 srd_h1hi = make_srd(h1hi, HBYTES);
  const i32x4 srd_h1lo = make_srd(h1lo, HBYTES);

  __shared__ short Ws[3 * 16 * 1024];   // 96 KiB: [Whh0 | Wih1 | Whh1], swizzled

  {
    const float* srcs[3] = { Whh0, Wih1, Whh1 };
    const int n = tid >> 5;             // 0..15
    const int kb = (tid & 31) * 32;     // 0..992
    #pragma unroll
    for (int mi = 0; mi < 3; ++mi) {
      const float* src = srcs[mi] + (size_t)(n0 + n) * RNN_H + kb;
      short* dst = &Ws[mi * 16 * 1024 + n * 1024];
      #pragma unroll
      for (int j = 0; j < 4; ++j) {
        float4 f0 = *(const float4*)(src + j * 8);
        float4 f1 = *(const float4*)(src + j * 8 + 4);
        float tmp[8]; *(float4*)&tmp[0] = f0; *(float4*)&tmp[4] = f1;
        bf16x8 hv, lv; cvt8_hl(tmp, &hv, &lv);
        const int c = (kb >> 3) + j;
        *(bf16x8*)&dst[((c ^ (n & 7)) << 3)] = hv;
      }
    }
  }
  const float bias1v = bih1[n0 + l15] + bhh1[n0 + l15];
  float* hT = outs + OUTS_ELEMS;
  __syncthreads();

  float a0v[4];
  if (!isL1) {
    #pragma unroll
    for (int r = 0; r < 4; ++r)
      a0v[r] = outs[((size_t)(mt + lq * 4 + r) * RNN_S + 0) * RNN_H + n0 + l15];
  }

  for (int p = 0; p <= RNN_S; ++p) {
    if (!isL1) {
      if (p < RNN_S) {
        // layer 0: h0(p) = tanh(A0[:,p,:] + h0(p-1) @ Whh0^T) for cols n0..n0+15
        f32x4 acc0 = { a0v[0], a0v[1], a0v[2], a0v[3] };
        f32x4 acc1 = {}, acc2 = {}, acc3 = {};
        if (p > 0) {
          const int hb = (((p - 1) & 1) * BH + (mt + l15) * RNN_H + lq * 8) * 2;
          const short* wrow = &Ws[l15 * 1024];
          const int swz = l15 & 7;
          #pragma unroll
          for (int ks = 0; ks < 16; ++ks) {   // 4 independent chains for ILP
            const int c0 = ((ks * 4 + lq) ^ swz) << 3;
            const int c1 = (((ks + 16) * 4 + lq) ^ swz) << 3;
            acc0 = mfma16(ld_h(srd_h0hi, hb + ks * 64),         *(const bf16x8*)(wrow + c0), acc0);
            acc1 = mfma16(ld_h(srd_h0hi, hb + (ks + 16) * 64),  *(const bf16x8*)(wrow + c1), acc1);
            acc2 = mfma16(ld_h(srd_h0lo, hb + ks * 64),         *(const bf16x8*)(wrow + c0), acc2);
            acc3 = mfma16(ld_h(srd_h0lo, hb + (ks + 16) * 64),  *(const bf16x8*)(wrow + c1), acc3);
          }
        }
        acc0 += acc1; acc2 += acc3; acc0 += acc2;
        float vals[4];
        #pragma unroll
        for (int r = 0; r < 4; ++r) vals[r] = tanhf(acc0[r]);
        const size_t hd = (size_t)(p & 1) * BH;
        #pragma unroll
        for (int r = 0; r < 4; ++r) {
          const int idx = (mt + lq * 4 + r) * RNN_H + n0 + l15;
          short hi = f2bf(vals[r]);
          st_sys_u16(&h0hi[hd + idx], (unsigned)(unsigned short)hi);
          st_sys_u16(&h0lo[hd + idx], (unsigned)(unsigned short)f2bf(vals[r] - bf2f(hi)));
        }
        if (p == RNN_S - 1) {
          #pragma unroll
          for (int r = 0; r < 4; ++r)
            hT[(size_t)(mt + lq * 4 + r) * RNN_H + n0 + l15] = vals[r];
        }
        if (p + 1 < RNN_S) {   // prefetch next A0 (barrier-independent; drains inside gbar)
          #pragma unroll
          for (int r = 0; r < 4; ++r)
            a0v[r] = outs[((size_t)(mt + lq * 4 + r) * RNN_S + (p + 1)) * RNN_H + n0 + l15];
        }
      }
    } else {
      if (p >= 1) {
        // layer 1: t = p-1: h1(t) = tanh(b1 + h0(t) @ Wih1^T + h1(t-1) @ Whh1^T)
        const int t = p - 1;
        f32x4 acc0 = { bias1v, bias1v, bias1v, bias1v };
        f32x4 acc1 = {}, acc2 = {}, acc3 = {};
        const int h0b = ((t & 1) * BH + (mt + l15) * RNN_H + lq * 8) * 2;
        const short* wih = &Ws[16 * 1024 + l15 * 1024];
        const short* whh = &Ws[2 * 16 * 1024 + l15 * 1024];
        const int swz = l15 & 7;
        if (t > 0) {
          const int h1b = (((t - 1) & 1) * BH + (mt + l15) * RNN_H + lq * 8) * 2;
          #pragma unroll
          for (int ks = 0; ks < 32; ++ks) {   // 4 independent chains
            const int c = ((ks * 4 + lq) ^ swz) << 3;
            acc0 = mfma16(ld_h(srd_h0hi, h0b + ks * 64), *(const bf16x8*)(wih + c), acc0);
            acc1 = mfma16(ld_h(srd_h0lo, h0b + ks * 64), *(const bf16x8*)(wih + c), acc1);
            acc2 = mfma16(ld_h(srd_h1hi, h1b + ks * 64), *(const bf16x8*)(whh + c), acc2);
            acc3 = mfma16(ld_h(srd_h1lo, h1b + ks * 64), *(const bf16x8*)(whh + c), acc3);
          }
        } else {
          #pragma unroll
          for (int ks = 0; ks < 32; ++ks) {
            const int c = ((ks * 4 + lq) ^ swz) << 3;
            acc0 = mfma16(ld_h(srd_h0hi, h0b + ks * 64), *(const bf16x8*)(wih + c), acc0);
            acc1 = mfma16(ld_h(srd_h0lo, h0b + ks * 64), *(const bf16x8*)(wih + c), acc1);
          }
        }
        acc0 += acc1; acc2 += acc3; acc0 += acc2;
        float vals[4];
        #pragma unroll
        for (int r = 0; r < 4; ++r) vals[r] = tanhf(acc0[r]);
        const size_t hd = (size_t)(t & 1) * BH;
        #pragma unroll
        for (int r = 0; r < 4; ++r) {
          const int b = mt + lq * 4 + r;
          const int idx = b * RNN_H + n0 + l15;
          short hi = f2bf(vals[r]);
          st_sys_u16(&h1hi[hd + idx], (unsigned)(unsigned short)hi);
          st_sys_u16(&h1lo[hd + idx], (unsigned)(unsigned short)f2bf(vals[r] - bf2f(hi)));
          outs[((size_t)b * RNN_S + t) * RNN_H + n0 + l15] = vals[r];
        }
        if (t == RNN_S - 1) {
          #pragma unroll
          for (int r = 0; r < 4; ++r)
            hT[(size_t)RNN_B * RNN_H + (mt + lq * 4 + r) * RNN_H + n0 + l15] = vals[r];
        }
      }
    }
    if (p < RNN_S) gbar(flags, (unsigned)(p + 1), bid);
  }
}

extern "C" void kernel_launch(void* const* d_in, const int* in_sizes, int n_in,
                              void* d_out, int out_size, void* d_ws, size_t ws_size,
                              hipStream_t stream) {
  const float* x    = (const float*)d_in[0];
  const float* Wih0 = (const float*)d_in[1];
  const float* bih0 = (const float*)d_in[2];
  const float* Whh0 = (const float*)d_in[3];
  const float* bhh0 = (const float*)d_in[4];
  const float* Wih1 = (const float*)d_in[5];
  const float* bih1 = (const float*)d_in[6];
  const float* Whh1 = (const float*)d_in[7];
  const float* bhh1 = (const float*)d_in[8];
  float* outs = (float*)d_out;

  const int BH2 = 2 * RNN_B * RNN_H;               // elems per ping-pong buffer
  short* h0hi = (short*)d_ws;
  short* h0lo = h0hi + BH2;
  short* h1hi = h0lo + BH2;
  short* h1lo = h1hi + BH2;
  unsigned* flags = (unsigned*)((char*)d_ws + ((size_t)4 * BH2 * sizeof(short)));

  a0_gemm<<<2048, 256, 0, stream>>>(x, Wih0, bih0, bhh0, outs, flags);
  rnn_rec<<<NBLK, 512, 0, stream>>>(Whh0, Wih1, bih1, Whh1, bhh1, outs,
                                    h0hi, h0lo, h1hi, h1lo, flags);
}